// Round 17
// baseline (49.248 us; speedup 1.0000x reference)
//
#include <hip/hip_runtime.h>

typedef _Float16 f16x2 __attribute__((ext_vector_type(2)));
typedef _Float16 f16x4_t __attribute__((ext_vector_type(4)));
typedef _Float16 f16x8 __attribute__((ext_vector_type(8)));
typedef float    floatx4 __attribute__((ext_vector_type(4)));

#define INV2PI 0.15915494309189535f
#define NCHAIN 4    // 16-pt chains per consumer per batch (64 pts)
#define NBATCH 8    // batches per block; block covers 2048 points

__device__ __forceinline__ f16x2 cvt_pk(float a, float b) {
    return __builtin_bit_cast(f16x2, __builtin_amdgcn_cvt_pkrtz(a, b));
}
__device__ __forceinline__ f16x2 pk_relu(f16x2 h) {
    f16x2 z; z[0] = (_Float16)0.f; z[1] = (_Float16)0.f;
    return __builtin_elementwise_max(h, z);       // v_pk_max_f16
}
__device__ __forceinline__ f16x4_t cat2(f16x2 a, f16x2 b) {
    return __builtin_shufflevector(a, b, 0, 1, 2, 3);
}
__device__ __forceinline__ f16x8 cat4(f16x4_t a, f16x4_t b) {
    return __builtin_shufflevector(a, b, 0, 1, 2, 3, 4, 5, 6, 7);
}

// N3R fused PE + 3-layer MLP — PRODUCER/CONSUMER wave specialization.
// Inputs f32 (harness upcast of f16 ref), output f32.
// Block = 512 thr: waves 0-3 producers (PE: coords -> B1 fragments -> LDS
// double buffer; pure VALU/trans), waves 4-7 consumers (B1 -> 3 MFMA layers
// with register-resident weights -> store; MFMA-dominant).  One barrier per
// 256-pt batch.  Transposed layers D^T = W^T(A) @ act^T(B) via
// mfma_f32_16x16x32_f16; inter-layer transpose = fused register repack
// (F(kk,g*8+i) = ((i>>2)+2kk)*16+g*4+(i&3), applied at weight load).
__global__ __launch_bounds__(512, 2) void nerf_pc_kernel(
    const float* __restrict__ coords,
    const float* __restrict__ W1, const float* __restrict__ b1,
    const float* __restrict__ W2, const float* __restrict__ b2,
    const float* __restrict__ W3, const float* __restrict__ b3,
    float* __restrict__ out, int npts)
{
    // weights: 14 frags x 64 lanes x 16 B = 14 KB
    __shared__ __align__(16) floatx4 wlds[14][64];
    // B1 double buffer: 2 x 4 consumers x 4 chains x 64 lanes x 16 B = 32 KB
    __shared__ __align__(16) floatx4 bbuf[2][4][NCHAIN][64];

    const int tid  = threadIdx.x;
    const int wave = tid >> 6;
    const int lane = tid & 63;
    const int m    = lane & 15;       // A row (out-feature) / B,D col (point)
    const int g    = lane >> 4;       // quarter-wave group (owns freq 2^g)

    const float sg = __builtin_amdgcn_ldexpf(INV2PI, g);   // 2^g / (2*pi)
    const long  blkbase = (long)blockIdx.x * 2048;

    // ---------------- stage weight fragments into LDS (waves 0-3) ---------
    // Layer-1 K-slot (g,i): i<6 -> enc feature 3+6g+3*(i>=3)+(i%3);
    // (0,6)=x0 (0,7)=x1 (1,6)=x2 (1,7)=bias row (enc==1); rest zero-pad.
    if (wave == 0) {
        #pragma unroll
        for (int t1 = 0; t1 < 4; ++t1) {
            int n = t1 * 16 + m;
            f16x8 v;
            #pragma unroll
            for (int i = 0; i < 8; ++i) {
                float w;
                if (i < 6)        w = W1[(3 + 6 * g + (i >= 3 ? 3 : 0) + (i % 3)) * 64 + n];
                else if (g == 0)  w = (i == 6) ? W1[0 * 64 + n] : W1[1 * 64 + n];
                else if (g == 1)  w = (i == 6) ? W1[2 * 64 + n] : b1[n];
                else              w = 0.f;
                v[i] = (_Float16)w;
            }
            wlds[t1][lane] = __builtin_bit_cast(floatx4, v);
        }
    } else if (wave == 1 || wave == 2) {
        #pragma unroll
        for (int tt2 = 0; tt2 < 2; ++tt2) {
            int t2 = (wave - 1) * 2 + tt2;
            int n = t2 * 16 + m;
            #pragma unroll
            for (int kk = 0; kk < 2; ++kk) {
                f16x8 v;
                #pragma unroll
                for (int i = 0; i < 8; ++i) {
                    int f = ((i >> 2) + 2 * kk) * 16 + g * 4 + (i & 3);
                    v[i] = (_Float16)W2[f * 64 + n];
                }
                wlds[4 + t2 * 2 + kk][lane] = __builtin_bit_cast(floatx4, v);
            }
        }
    } else if (wave == 3) {
        #pragma unroll
        for (int kk = 0; kk < 2; ++kk) {
            f16x8 v;
            #pragma unroll
            for (int i = 0; i < 8; ++i) {
                int f = ((i >> 2) + 2 * kk) * 16 + g * 4 + (i & 3);
                v[i] = (_Float16)((m < 4) ? W3[f * 4 + m] : 0.f);
            }
            wlds[12 + kk][lane] = __builtin_bit_cast(floatx4, v);
        }
    }

    // consumer-only biases (global scalar loads, no sync needed)
    floatx4 bias2q[4];
    #pragma unroll
    for (int t2 = 0; t2 < 4; ++t2)
        #pragma unroll
        for (int r = 0; r < 4; ++r)
            bias2q[t2][r] = b2[t2 * 16 + g * 4 + r];
    floatx4 bias3q;
    #pragma unroll
    for (int r = 0; r < 4; ++r)
        bias3q[r] = (g == 0) ? b3[r] : 0.f;

    const int role_prod = (wave < 4);
    const int c = role_prod ? wave : (wave - 4);   // consumer/producer pair id

    // producer: build B1 fragments for batch b into bbuf[b&1][c]
    auto produce = [&](int b) {
        const long pb = blkbase + (long)b * 256 + (long)c * 64;
        #pragma unroll
        for (int p = 0; p < NCHAIN; ++p) {
            const long cb = (pb + p * 16 + m) * 3;
            float x0 = coords[cb + 0], x1 = coords[cb + 1], x2 = coords[cb + 2];
            float s[6];
            #pragma unroll
            for (int i = 0; i < 6; ++i) {
                float xv = (i % 3 == 0) ? x0 : ((i % 3 == 1) ? x1 : x2);
                float ph = (i >= 3) ? 0.25f : 0.f;
                s[i] = __builtin_amdgcn_sinf(fmaf(xv, sg, ph));
            }
            float v6 = (g == 0) ? x0 : ((g == 1) ? x2 : 0.f);
            float v7 = (g == 0) ? x1 : ((g == 1) ? 1.f : 0.f);
            f16x8 B1 = cat4(cat2(cvt_pk(s[0], s[1]), cvt_pk(s[2], s[3])),
                            cat2(cvt_pk(s[4], s[5]), cvt_pk(v6, v7)));
            bbuf[b & 1][c][p][lane] = __builtin_bit_cast(floatx4, B1);
        }
    };

    // prologue: producers build batch 0 (weights staged above, same waves)
    if (role_prod) produce(0);
    __syncthreads();

    for (int b = 0; b < NBATCH; ++b) {
        if (role_prod) {
            if (b + 1 < NBATCH) produce(b + 1);
        } else {
            // ---- consumer: weights are loop-invariant -> LICM to registers
            f16x8 A1v[4], A2v[4][2], A3v[2];
            #pragma unroll
            for (int t1 = 0; t1 < 4; ++t1)
                A1v[t1] = __builtin_bit_cast(f16x8, wlds[t1][lane]);
            #pragma unroll
            for (int t2 = 0; t2 < 4; ++t2)
                #pragma unroll
                for (int kk = 0; kk < 2; ++kk)
                    A2v[t2][kk] = __builtin_bit_cast(f16x8, wlds[4 + t2 * 2 + kk][lane]);
            #pragma unroll
            for (int kk = 0; kk < 2; ++kk)
                A3v[kk] = __builtin_bit_cast(f16x8, wlds[12 + kk][lane]);

            f16x8 B1[NCHAIN];
            #pragma unroll
            for (int p = 0; p < NCHAIN; ++p)
                B1[p] = __builtin_bit_cast(f16x8, bbuf[b & 1][c][p][lane]);

            // ---- layer 1, fused repack -----------------------------------
            f16x4_t h1q[NCHAIN][4];
            #pragma unroll
            for (int t1 = 0; t1 < 4; ++t1)
                #pragma unroll
                for (int p = 0; p < NCHAIN; ++p) {
                    floatx4 a = (floatx4){0.f, 0.f, 0.f, 0.f};
                    a = __builtin_amdgcn_mfma_f32_16x16x32_f16(A1v[t1], B1[p], a, 0, 0, 0);
                    h1q[p][t1] = cat2(pk_relu(cvt_pk(a[0], a[1])),
                                      pk_relu(cvt_pk(a[2], a[3])));
                }
            f16x8 B2[NCHAIN][2];
            #pragma unroll
            for (int p = 0; p < NCHAIN; ++p)
                #pragma unroll
                for (int kk = 0; kk < 2; ++kk)
                    B2[p][kk] = cat4(h1q[p][2 * kk], h1q[p][2 * kk + 1]);

            // ---- layer 2, bias2 as C-in, fused repack --------------------
            f16x4_t h2q[NCHAIN][4];
            #pragma unroll
            for (int t2 = 0; t2 < 4; ++t2)
                #pragma unroll
                for (int p = 0; p < NCHAIN; ++p) {
                    floatx4 a = bias2q[t2];
                    a = __builtin_amdgcn_mfma_f32_16x16x32_f16(A2v[t2][0], B2[p][0], a, 0, 0, 0);
                    a = __builtin_amdgcn_mfma_f32_16x16x32_f16(A2v[t2][1], B2[p][1], a, 0, 0, 0);
                    h2q[p][t2] = cat2(pk_relu(cvt_pk(a[0], a[1])),
                                      pk_relu(cvt_pk(a[2], a[3])));
                }
            f16x8 B3[NCHAIN][2];
            #pragma unroll
            for (int p = 0; p < NCHAIN; ++p)
                #pragma unroll
                for (int kk = 0; kk < 2; ++kk)
                    B3[p][kk] = cat4(h2q[p][2 * kk], h2q[p][2 * kk + 1]);

            // ---- layer 3 + store -----------------------------------------
            const long pb = blkbase + (long)b * 256 + (long)c * 64;
            #pragma unroll
            for (int p = 0; p < NCHAIN; ++p) {
                floatx4 acc3 = bias3q;
                acc3 = __builtin_amdgcn_mfma_f32_16x16x32_f16(A3v[0], B3[p][0], acc3, 0, 0, 0);
                acc3 = __builtin_amdgcn_mfma_f32_16x16x32_f16(A3v[1], B3[p][1], acc3, 0, 0, 0);
                if (g == 0)
                    *reinterpret_cast<floatx4*>(&out[(pb + p * 16 + m) * 4]) = acc3;
            }
        }
        __syncthreads();   // batch fence: buf[b&1] free, buf[(b+1)&1] ready
    }
}

extern "C" void kernel_launch(void* const* d_in, const int* in_sizes, int n_in,
                              void* d_out, int out_size, void* d_ws, size_t ws_size,
                              hipStream_t stream) {
    const float* coords = (const float*)d_in[0];
    const float* W1 = (const float*)d_in[1];
    const float* b1 = (const float*)d_in[2];
    const float* W2 = (const float*)d_in[3];
    const float* b2 = (const float*)d_in[4];
    const float* W3 = (const float*)d_in[5];
    const float* b3 = (const float*)d_in[6];
    float* outp = (float*)d_out;

    const int npts = in_sizes[0] / 3;           // 2,097,152 = 1024 * 2048
    const int nblocks = 1024;
    hipLaunchKernelGGL(nerf_pc_kernel, dim3(nblocks), dim3(512), 0, stream,
                       coords, W1, b1, W2, b2, W3, b3, outp, npts);
}

// Round 18
// 41.054 us; speedup vs baseline: 1.1996x; 1.1996x over previous
//
#include <hip/hip_runtime.h>

typedef _Float16 f16x2 __attribute__((ext_vector_type(2)));
typedef _Float16 f16x4_t __attribute__((ext_vector_type(4)));
typedef _Float16 f16x8 __attribute__((ext_vector_type(8)));
typedef float    floatx4 __attribute__((ext_vector_type(4)));

#define INV2PI 0.15915494309189535f
#define NP 2   // independent 16-point chains per wave-iteration

__device__ __forceinline__ f16x2 cvt_pk(float a, float b) {
    return __builtin_bit_cast(f16x2, __builtin_amdgcn_cvt_pkrtz(a, b));
}
__device__ __forceinline__ f16x2 pk_relu(f16x2 h) {
    f16x2 z; z[0] = (_Float16)0.f; z[1] = (_Float16)0.f;
    return __builtin_elementwise_max(h, z);       // v_pk_max_f16
}
__device__ __forceinline__ f16x4_t cat2(f16x2 a, f16x2 b) {
    return __builtin_shufflevector(a, b, 0, 1, 2, 3);
}
__device__ __forceinline__ f16x8 cat4(f16x4_t a, f16x4_t b) {
    return __builtin_shufflevector(a, b, 0, 1, 2, 3, 4, 5, 6, 7);
}

// N3R fused PE + 3-layer MLP.  Inputs f32 (harness upcast of f16 ref),
// output f32.  Transposed layers D^T = W^T(A) @ act^T(B) via
// mfma_f32_16x16x32_f16; inter-layer transpose = fused register repack
// (F(kk,g*8+i) = ((i>>2)+2kk)*16+g*4+(i&3), applied at weight load).
// Weights LDS-resident (conflict-free ds_read_b128; opaque-index anti-LICM).
// NEW: __launch_bounds__(256,5) forces the UNIFIED VGPR+AGPR budget to
// <=102 regs/wave -> 5 waves/SIMD (occupancy was capped ~2.5-3.5 waves by
// ~100 hidden AGPRs).  Register diet: packed-f16 bias2 (pk_add, r11-verified
// numerics), shared zero4 C-operand (MFMA D!=C, no per-iter acc-init copies).
__global__ __launch_bounds__(256, 5) void nerf_fused_kernel(
    const float* __restrict__ coords,
    const float* __restrict__ W1, const float* __restrict__ b1,
    const float* __restrict__ W2, const float* __restrict__ b2,
    const float* __restrict__ W3, const float* __restrict__ b3,
    float* __restrict__ out, int npts)
{
    // 14 fragments x 64 lanes x 16 B = 14 KB
    __shared__ __align__(16) floatx4 wlds[14][64];

    const int tid  = threadIdx.x;
    const int wave = tid >> 6;
    const int lane = tid & 63;
    const int m    = lane & 15;       // A row (out-feature) / B,D col (point)
    const int g    = lane >> 4;       // quarter-wave group (owns freq 2^g)

    // ---------------- stage weight fragments into LDS (waves 0 & 1) -------
    // Layer-1 K-slot (g,i): i<6 -> enc feature 3+6g+3*(i>=3)+(i%3);
    // (0,6)=x0 (0,7)=x1 (1,6)=x2 (1,7)=bias row (enc==1); rest zero-pad.
    if (wave == 0) {
        #pragma unroll
        for (int t1 = 0; t1 < 4; ++t1) {
            int n = t1 * 16 + m;
            f16x8 v;
            #pragma unroll
            for (int i = 0; i < 8; ++i) {
                float w;
                if (i < 6)        w = W1[(3 + 6 * g + (i >= 3 ? 3 : 0) + (i % 3)) * 64 + n];
                else if (g == 0)  w = (i == 6) ? W1[0 * 64 + n] : W1[1 * 64 + n];
                else if (g == 1)  w = (i == 6) ? W1[2 * 64 + n] : b1[n];
                else              w = 0.f;
                v[i] = (_Float16)w;
            }
            wlds[t1][lane] = __builtin_bit_cast(floatx4, v);
        }
        #pragma unroll
        for (int kk = 0; kk < 2; ++kk) {
            f16x8 v;
            #pragma unroll
            for (int i = 0; i < 8; ++i) {
                int f = ((i >> 2) + 2 * kk) * 16 + g * 4 + (i & 3);
                v[i] = (_Float16)((m < 4) ? W3[f * 4 + m] : 0.f);
            }
            wlds[12 + kk][lane] = __builtin_bit_cast(floatx4, v);
        }
    } else if (wave == 1) {
        #pragma unroll
        for (int t2 = 0; t2 < 4; ++t2) {
            int n = t2 * 16 + m;
            #pragma unroll
            for (int kk = 0; kk < 2; ++kk) {
                f16x8 v;
                #pragma unroll
                for (int i = 0; i < 8; ++i) {
                    int f = ((i >> 2) + 2 * kk) * 16 + g * 4 + (i & 3);
                    v[i] = (_Float16)W2[f * 64 + n];
                }
                wlds[4 + t2 * 2 + kk][lane] = __builtin_bit_cast(floatx4, v);
            }
        }
    }
    __syncthreads();

    // lean persistent set: packed-f16 bias2 (8 regs), f32 bias3 C-op (4),
    // shared zero C-op (4)
    f16x2 b2pk[4][2];
    #pragma unroll
    for (int t2 = 0; t2 < 4; ++t2)
        #pragma unroll
        for (int h = 0; h < 2; ++h)
            b2pk[t2][h] = cvt_pk(b2[t2 * 16 + g * 4 + 2 * h],
                                 b2[t2 * 16 + g * 4 + 2 * h + 1]);
    floatx4 bias3q;
    #pragma unroll
    for (int r = 0; r < 4; ++r)
        bias3q[r] = (g == 0) ? b3[r] : 0.f;
    const floatx4 zero4 = (floatx4){0.f, 0.f, 0.f, 0.f};

    const float sg = __builtin_amdgcn_ldexpf(INV2PI, g);   // 2^g / (2*pi)

    // ---------------- counted main loop: 32 pts (2 chains) per iter -------
    const int  ntile = npts >> 5;               // 65536 tiles of 32 pts
    const int  gw    = blockIdx.x * 4 + wave;   // 8192 waves
    const int  nw    = gridDim.x * 4;
    const int  niter = ntile / nw;              // 8, uniform across waves

    // strength-reduced per-lane base pointers (chain offsets imm-foldable)
    const char* cptr = (const char*)coords + ((long)(gw << 5) + m) * 12;
    char*       optr = (char*)out + ((long)(gw << 5) + m) * 16;
    const long  cstride = (long)nw * 32 * 12;   // bytes per iteration
    const long  ostride = (long)nw * 32 * 16;

    float cx[NP][3];
    #pragma unroll
    for (int p = 0; p < NP; ++p)
        #pragma unroll
        for (int j = 0; j < 3; ++j)
            cx[p][j] = *(const float*)(cptr + p * 192 + j * 4);
    cptr += cstride;

    for (int it = 0; it < niter; ++it) {
        // opaque zero: weight loads stay loop-variant -> no LICM re-hoist
        unsigned fr0 = 0;
        asm volatile("" : "+v"(fr0));
        const floatx4* wp = &wlds[0][0] + fr0 + lane;

        // ---- PE -> B1 fragments ------------------------------------------
        f16x8 B1[NP];
        #pragma unroll
        for (int p = 0; p < NP; ++p) {
            float s[6];
            #pragma unroll
            for (int i = 0; i < 6; ++i) {
                float xv = cx[p][i % 3];
                float ph = (i >= 3) ? 0.25f : 0.f;
                s[i] = __builtin_amdgcn_sinf(fmaf(xv, sg, ph));
            }
            float v6 = (g == 0) ? cx[p][0] : ((g == 1) ? cx[p][2] : 0.f);
            float v7 = (g == 0) ? cx[p][1] : ((g == 1) ? 1.f : 0.f);
            B1[p] = cat4(cat2(cvt_pk(s[0], s[1]), cvt_pk(s[2], s[3])),
                         cat2(cvt_pk(s[4], s[5]), cvt_pk(v6, v7)));
        }

        // ---- prefetch next iteration's coords (uniform guard) ------------
        if (it + 1 < niter) {
            #pragma unroll
            for (int p = 0; p < NP; ++p)
                #pragma unroll
                for (int j = 0; j < 3; ++j)
                    cx[p][j] = *(const float*)(cptr + p * 192 + j * 4);
            cptr += cstride;
        }

        __builtin_amdgcn_s_setprio(1);          // MFMA+repack phase

        // ---- layer 1, fused repack: acc(t1,p) -> quarter of B2 -----------
        f16x4_t h1q[NP][4];
        #pragma unroll
        for (int t1 = 0; t1 < 4; ++t1) {
            f16x8 A1v = __builtin_bit_cast(f16x8, wp[t1 * 64]);
            #pragma unroll
            for (int p = 0; p < NP; ++p) {
                floatx4 a = __builtin_amdgcn_mfma_f32_16x16x32_f16(A1v, B1[p], zero4, 0, 0, 0);
                h1q[p][t1] = cat2(pk_relu(cvt_pk(a[0], a[1])),
                                  pk_relu(cvt_pk(a[2], a[3])));
            }
        }
        f16x8 B2[NP][2];
        #pragma unroll
        for (int p = 0; p < NP; ++p)
            #pragma unroll
            for (int kk = 0; kk < 2; ++kk)
                B2[p][kk] = cat4(h1q[p][2 * kk], h1q[p][2 * kk + 1]);

        // ---- layer 2, fused repack (+bias2 as packed-f16 add) ------------
        f16x4_t h2q[NP][4];
        #pragma unroll
        for (int t2 = 0; t2 < 4; ++t2) {
            f16x8 A2v0 = __builtin_bit_cast(f16x8, wp[(4 + t2 * 2) * 64]);
            f16x8 A2v1 = __builtin_bit_cast(f16x8, wp[(5 + t2 * 2) * 64]);
            #pragma unroll
            for (int p = 0; p < NP; ++p) {
                floatx4 a = __builtin_amdgcn_mfma_f32_16x16x32_f16(A2v0, B2[p][0], zero4, 0, 0, 0);
                a = __builtin_amdgcn_mfma_f32_16x16x32_f16(A2v1, B2[p][1], a, 0, 0, 0);
                f16x2 lo = pk_relu(cvt_pk(a[0], a[1]) + b2pk[t2][0]);
                f16x2 hi = pk_relu(cvt_pk(a[2], a[3]) + b2pk[t2][1]);
                h2q[p][t2] = cat2(lo, hi);
            }
        }
        f16x8 B3[NP][2];
        #pragma unroll
        for (int p = 0; p < NP; ++p)
            #pragma unroll
            for (int kk = 0; kk < 2; ++kk)
                B3[p][kk] = cat4(h2q[p][2 * kk], h2q[p][2 * kk + 1]);

        // ---- layer 3 + store ---------------------------------------------
        f16x8 A3v0 = __builtin_bit_cast(f16x8, wp[12 * 64]);
        f16x8 A3v1 = __builtin_bit_cast(f16x8, wp[13 * 64]);
        #pragma unroll
        for (int p = 0; p < NP; ++p) {
            floatx4 acc3 = __builtin_amdgcn_mfma_f32_16x16x32_f16(A3v0, B3[p][0], bias3q, 0, 0, 0);
            acc3 = __builtin_amdgcn_mfma_f32_16x16x32_f16(A3v1, B3[p][1], acc3, 0, 0, 0);
            if (g == 0)
                *(floatx4*)(optr + p * 256) = acc3;
        }
        optr += ostride;

        __builtin_amdgcn_s_setprio(0);          // back to PE phase
    }
}

extern "C" void kernel_launch(void* const* d_in, const int* in_sizes, int n_in,
                              void* d_out, int out_size, void* d_ws, size_t ws_size,
                              hipStream_t stream) {
    const float* coords = (const float*)d_in[0];
    const float* W1 = (const float*)d_in[1];
    const float* b1 = (const float*)d_in[2];
    const float* W2 = (const float*)d_in[3];
    const float* b2 = (const float*)d_in[4];
    const float* W3 = (const float*)d_in[5];
    const float* b3 = (const float*)d_in[6];
    float* outp = (float*)d_out;

    const int npts = in_sizes[0] / 3;           // 2,097,152
    const int nblocks = 2048;                   // 8192 waves; 65536/8192 = 8 iters
    hipLaunchKernelGGL(nerf_fused_kernel, dim3(nblocks), dim3(256), 0, stream,
                       coords, W1, b1, W2, b2, W3, b3, outp, npts);
}

// Round 19
// 39.247 us; speedup vs baseline: 1.2548x; 1.0460x over previous
//
#include <hip/hip_runtime.h>

typedef _Float16 f16x2 __attribute__((ext_vector_type(2)));
typedef _Float16 f16x8 __attribute__((ext_vector_type(8)));
typedef float    floatx4 __attribute__((ext_vector_type(4)));
typedef unsigned uintx4 __attribute__((ext_vector_type(4)));

#define INV2PI 0.15915494309189535f
#define NP 4   // independent 16-point chains per wave-iteration

__device__ __forceinline__ unsigned cvt_pk_u(float a, float b) {
    return __builtin_bit_cast(unsigned, __builtin_amdgcn_cvt_pkrtz(a, b));
}
__device__ __forceinline__ unsigned pk_relu_u(unsigned hu) {
    f16x2 h = __builtin_bit_cast(f16x2, hu);
    f16x2 z; z[0] = (_Float16)0.f; z[1] = (_Float16)0.f;
    return __builtin_bit_cast(unsigned, __builtin_elementwise_max(h, z));
}

// N3R fused PE + 3-layer MLP.  Inputs f32 (harness upcast of f16 ref),
// output f32.  Transposed layers D^T = W^T(A) @ act^T(B) via
// mfma_f32_16x16x32_f16; inter-layer transpose = fused register repack
// (F(kk,g*8+i) = ((i>>2)+2kk)*16+g*4+(i&3), applied at weight load).
// Weights LDS-resident (conflict-free ds_read_b128; opaque-index anti-LICM).
// NEW vs r16: fragment construction is MOVE-FREE — each cvt_pkrtz result is
// written directly into its final 32-bit slot of a uint4 that IS the next
// layer's B-fragment (loop order kk-outer/tt-inner so producer order ==
// consumer slot order); the h1q/h2q arrays and cat2/cat4 shuffles are gone.
__global__ __launch_bounds__(512, 4) void nerf_fused_kernel(
    const float* __restrict__ coords,
    const float* __restrict__ W1, const float* __restrict__ b1,
    const float* __restrict__ W2, const float* __restrict__ b2,
    const float* __restrict__ W3, const float* __restrict__ b3,
    float* __restrict__ out, int npts)
{
    // 14 fragments x 64 lanes x 16 B = 14 KB (shared by all 8 waves)
    __shared__ __align__(16) floatx4 wlds[14][64];

    const int tid  = threadIdx.x;
    const int wave = tid >> 6;
    const int lane = tid & 63;
    const int m    = lane & 15;       // A row (out-feature) / B,D col (point)
    const int g    = lane >> 4;       // quarter-wave group (owns freq 2^g)

    // ---------------- stage weight fragments into LDS (waves 0 & 1) -------
    // Layer-1 K-slot (g,i): i<6 -> enc feature 3+6g+3*(i>=3)+(i%3);
    // (0,6)=x0 (0,7)=x1 (1,6)=x2 (1,7)=bias row (enc==1); rest zero-pad.
    if (wave == 0) {
        #pragma unroll
        for (int t1 = 0; t1 < 4; ++t1) {
            int n = t1 * 16 + m;
            f16x8 v;
            #pragma unroll
            for (int i = 0; i < 8; ++i) {
                float w;
                if (i < 6)        w = W1[(3 + 6 * g + (i >= 3 ? 3 : 0) + (i % 3)) * 64 + n];
                else if (g == 0)  w = (i == 6) ? W1[0 * 64 + n] : W1[1 * 64 + n];
                else if (g == 1)  w = (i == 6) ? W1[2 * 64 + n] : b1[n];
                else              w = 0.f;
                v[i] = (_Float16)w;
            }
            wlds[t1][lane] = __builtin_bit_cast(floatx4, v);
        }
        #pragma unroll
        for (int kk = 0; kk < 2; ++kk) {
            f16x8 v;
            #pragma unroll
            for (int i = 0; i < 8; ++i) {
                int f = ((i >> 2) + 2 * kk) * 16 + g * 4 + (i & 3);
                v[i] = (_Float16)((m < 4) ? W3[f * 4 + m] : 0.f);
            }
            wlds[12 + kk][lane] = __builtin_bit_cast(floatx4, v);
        }
    } else if (wave == 1) {
        #pragma unroll
        for (int t2 = 0; t2 < 4; ++t2) {
            int n = t2 * 16 + m;
            #pragma unroll
            for (int kk = 0; kk < 2; ++kk) {
                f16x8 v;
                #pragma unroll
                for (int i = 0; i < 8; ++i) {
                    int f = ((i >> 2) + 2 * kk) * 16 + g * 4 + (i & 3);
                    v[i] = (_Float16)W2[f * 64 + n];
                }
                wlds[4 + t2 * 2 + kk][lane] = __builtin_bit_cast(floatx4, v);
            }
        }
    }
    __syncthreads();

    // biases as f32 MFMA C-init (zero per-iter VALU)
    floatx4 bias2q[4];
    #pragma unroll
    for (int t2 = 0; t2 < 4; ++t2)
        #pragma unroll
        for (int r = 0; r < 4; ++r)
            bias2q[t2][r] = b2[t2 * 16 + g * 4 + r];
    floatx4 bias3q;
    #pragma unroll
    for (int r = 0; r < 4; ++r)
        bias3q[r] = (g == 0) ? b3[r] : 0.f;
    const floatx4 zero4 = (floatx4){0.f, 0.f, 0.f, 0.f};

    const float sg = __builtin_amdgcn_ldexpf(INV2PI, g);   // 2^g / (2*pi)

    // ---------------- counted main loop: 64 pts (4 chains) per iter -------
    const int  ntile = npts >> 6;               // 32768 tiles of 64 pts
    const int  gw    = blockIdx.x * 8 + wave;   // 8192 waves
    const int  nw    = gridDim.x * 8;
    const int  niter = ntile / nw;              // 4, uniform across waves

    // strength-reduced per-lane base pointers (chain offsets imm-foldable)
    const char* cptr = (const char*)coords + ((long)(gw << 6) + m) * 12;
    char*       optr = (char*)out + ((long)(gw << 6) + m) * 16;
    const long  cstride = (long)nw * 64 * 12;   // bytes per iteration
    const long  ostride = (long)nw * 64 * 16;

    float cx[NP][3];
    #pragma unroll
    for (int p = 0; p < NP; ++p)
        #pragma unroll
        for (int j = 0; j < 3; ++j)
            cx[p][j] = *(const float*)(cptr + p * 192 + j * 4);
    cptr += cstride;

    for (int it = 0; it < niter; ++it) {
        // opaque zero: weight loads stay loop-variant -> no LICM re-hoist
        unsigned fr0 = 0;
        asm volatile("" : "+v"(fr0));
        const floatx4* wp = &wlds[0][0] + fr0 + lane;

        // ---- PE -> B1 fragments (direct slot writes) ---------------------
        f16x8 B1[NP];
        #pragma unroll
        for (int p = 0; p < NP; ++p) {
            float s[6];
            #pragma unroll
            for (int i = 0; i < 6; ++i) {
                float xv = cx[p][i % 3];
                float ph = (i >= 3) ? 0.25f : 0.f;
                s[i] = __builtin_amdgcn_sinf(fmaf(xv, sg, ph));
            }
            float v6 = (g == 0) ? cx[p][0] : ((g == 1) ? cx[p][2] : 0.f);
            float v7 = (g == 0) ? cx[p][1] : ((g == 1) ? 1.f : 0.f);
            uintx4 b1u;
            b1u[0] = cvt_pk_u(s[0], s[1]);
            b1u[1] = cvt_pk_u(s[2], s[3]);
            b1u[2] = cvt_pk_u(s[4], s[5]);
            b1u[3] = cvt_pk_u(v6, v7);
            B1[p] = __builtin_bit_cast(f16x8, b1u);
        }

        // ---- prefetch next iteration's coords (uniform guard) ------------
        if (it + 1 < niter) {
            #pragma unroll
            for (int p = 0; p < NP; ++p)
                #pragma unroll
                for (int j = 0; j < 3; ++j)
                    cx[p][j] = *(const float*)(cptr + p * 192 + j * 4);
            cptr += cstride;
        }

        __builtin_amdgcn_s_setprio(1);          // MFMA+repack phase

        // ---- layer 1: produce B2 words in final slot order ---------------
        // B2[p][kk] word (2*tt+j) <- relu(acc1[t1=2kk+tt] elems 2j,2j+1)
        f16x8 B2[NP][2];
        #pragma unroll
        for (int kk = 0; kk < 2; ++kk) {
            uintx4 b2u[NP];
            #pragma unroll
            for (int tt = 0; tt < 2; ++tt) {
                f16x8 A1v = __builtin_bit_cast(f16x8, wp[(2 * kk + tt) * 64]);
                #pragma unroll
                for (int p = 0; p < NP; ++p) {
                    floatx4 a = __builtin_amdgcn_mfma_f32_16x16x32_f16(A1v, B1[p], zero4, 0, 0, 0);
                    b2u[p][2 * tt + 0] = pk_relu_u(cvt_pk_u(a[0], a[1]));
                    b2u[p][2 * tt + 1] = pk_relu_u(cvt_pk_u(a[2], a[3]));
                }
            }
            #pragma unroll
            for (int p = 0; p < NP; ++p)
                B2[p][kk] = __builtin_bit_cast(f16x8, b2u[p]);
        }

        // ---- layer 2: produce B3 words in final slot order (bias2 C-in) --
        f16x8 B3[NP][2];
        #pragma unroll
        for (int kk = 0; kk < 2; ++kk) {
            uintx4 b3u[NP];
            #pragma unroll
            for (int tt = 0; tt < 2; ++tt) {
                int t2 = 2 * kk + tt;
                f16x8 A2v0 = __builtin_bit_cast(f16x8, wp[(4 + t2 * 2) * 64]);
                f16x8 A2v1 = __builtin_bit_cast(f16x8, wp[(5 + t2 * 2) * 64]);
                #pragma unroll
                for (int p = 0; p < NP; ++p) {
                    floatx4 a = __builtin_amdgcn_mfma_f32_16x16x32_f16(A2v0, B2[p][0], bias2q[t2], 0, 0, 0);
                    a = __builtin_amdgcn_mfma_f32_16x16x32_f16(A2v1, B2[p][1], a, 0, 0, 0);
                    b3u[p][2 * tt + 0] = pk_relu_u(cvt_pk_u(a[0], a[1]));
                    b3u[p][2 * tt + 1] = pk_relu_u(cvt_pk_u(a[2], a[3]));
                }
            }
            #pragma unroll
            for (int p = 0; p < NP; ++p)
                B3[p][kk] = __builtin_bit_cast(f16x8, b3u[p]);
        }

        // ---- layer 3 + store ---------------------------------------------
        f16x8 A3v0 = __builtin_bit_cast(f16x8, wp[12 * 64]);
        f16x8 A3v1 = __builtin_bit_cast(f16x8, wp[13 * 64]);
        #pragma unroll
        for (int p = 0; p < NP; ++p) {
            floatx4 acc3 = __builtin_amdgcn_mfma_f32_16x16x32_f16(A3v0, B3[p][0], bias3q, 0, 0, 0);
            acc3 = __builtin_amdgcn_mfma_f32_16x16x32_f16(A3v1, B3[p][1], acc3, 0, 0, 0);
            if (g == 0)
                *(floatx4*)(optr + p * 256) = acc3;
        }
        optr += ostride;

        __builtin_amdgcn_s_setprio(0);          // back to PE phase
    }
}

extern "C" void kernel_launch(void* const* d_in, const int* in_sizes, int n_in,
                              void* d_out, int out_size, void* d_ws, size_t ws_size,
                              hipStream_t stream) {
    const float* coords = (const float*)d_in[0];
    const float* W1 = (const float*)d_in[1];
    const float* b1 = (const float*)d_in[2];
    const float* W2 = (const float*)d_in[3];
    const float* b2 = (const float*)d_in[4];
    const float* W3 = (const float*)d_in[5];
    const float* b3 = (const float*)d_in[6];
    float* outp = (float*)d_out;

    const int npts = in_sizes[0] / 3;           // 2,097,152
    const int nblocks = 1024;                   // 8192 waves; 32768/8192 = 4 iters
    hipLaunchKernelGGL(nerf_fused_kernel, dim3(nblocks), dim3(512), 0, stream,
                       coords, W1, b1, W2, b2, W3, b3, outp, npts);
}